// Round 10
// baseline (337.923 us; speedup 1.0000x reference)
//
#include <hip/hip_runtime.h>

#define NWIN 4096
#define EPSF 1e-6f
#define GRID_MAIN 512
#define BLOCK_MAIN 512

// fixed-point scales (u32 LDS atomics; native ds_add_u32)
#define SCALE_P   2097152.0f     // 2^21  sum_p
#define SCALE_R   131072.0f      // 2^17  agg_rate / sum_pd
#define INV_P     (1.0/2097152.0)
#define INV_R     (1.0/131072.0)
#define SCALE_CE  1048576.0f     // 2^20  CE num/den (scales cancel)

// ---------------- workspace layout (bytes) ----------------
//  byte 0:  u64 ce_num        byte 8:  u64 ce_den
//  byte 16: u32 n_valid(u[4]) byte 20: u32 n_mask(u[5])
//  byte 24: f32 ref_dobs(f[6]) byte 28: f32 frac(f[7])
//  byte 32,36: u32 prefixes (u[8],u[9])  byte 40,44: u32 ranks (u[10],u[11])
#define OFF_SEG   256            // float g_seg[16384] interleaved [wi*4+c]
#define OFF_H1    65792          // u32[2048]
#define OFF_H2    73984          // u32[2*2048]
#define OFF_H3    90368          // u32[2*1024]
#define OFF_SEGU  131072         // u32 g_seg_u32[16384] interleaved
#define OFF_PART  262144         // part(32MB) | keys | staged inputs

__device__ __forceinline__ unsigned make_key_raw(const float2* __restrict__ xzw,
                                                 const int* __restrict__ mask,
                                                 const int* __restrict__ widx, int i)
{
    int wi = widx[i];
    int m = mask[i];
    if (wi < 0 || !m) return 0x7F800000u;
    float d = fmaxf(xzw[2 * i + 1].x, 0.0f);
    unsigned k = __float_as_uint(d);
    return (k == 0x80000000u) ? 0u : k;
}

// ---------------- per-element fused work (branchless) ----------------
__device__ __forceinline__ void process_elem(
    float lgx, float lgy, int yi, int mi, float xz, float xw, int wi,
    float cw0, float cw1, unsigned* keyOut,
    float& num, float& den, unsigned& nv, unsigned& nm, unsigned& zc,
    unsigned* s_seg, unsigned* s_h1)
{
    float d = lgx - lgy;
    float ad = fabsf(d);
    float t = __expf(-ad);
    float inv1t = 1.0f / (1.0f + t);
    float l1p = __logf(1.0f + t);
    float s = yi ? d : -d;
    float nll = fmaxf(s, 0.0f) + l1p;
    float maskf = mi ? 1.0f : 0.0f;
    float wy = (yi ? cw1 : cw0) * maskf;
    nm += (mi != 0);
    num += wy * nll;
    den += wy;

    bool vq = (wi >= 0) && mi;
    float dob = fmaxf(xz, 0.0f);
    unsigned kraw = __float_as_uint(dob);
    kraw = (kraw == 0x80000000u) ? 0u : kraw;
    unsigned key = vq ? kraw : 0x7F800000u;
    *keyOut = key;
    nv += vq;
    zc += (key == 0u);

    atomicAdd(&s_h1[key >> 21], (key != 0u) ? 1u : 0u);

    bool sv = vq && ((unsigned)wi < NWIN);
    float sf = sv ? 1.0f : 0.0f;
    unsigned b = sv ? ((unsigned)wi << 2) : (4u * NWIN);
    float p = ((d > 0.0f) ? t : 1.0f) * inv1t;
    float rate = fmaxf(xw, 0.0f);
    atomicAdd(&s_seg[b],     sv ? 1u : 0u);
    atomicAdd(&s_seg[b | 1], (unsigned)(sf * p * SCALE_P + 0.5f));
    atomicAdd(&s_seg[b | 2], (unsigned)(sf * p * rate * SCALE_R + 0.5f));
    atomicAdd(&s_seg[b | 3], (unsigned)(sf * p * dob * SCALE_R + 0.5f));
}

// ---------------- main fused pass ----------------
extern "C" __global__ __launch_bounds__(BLOCK_MAIN)
void k_main(const float2* __restrict__ logits, const int* __restrict__ y,
            const int* __restrict__ mask, const float2* __restrict__ xzw,
            const int* __restrict__ widx, const float* __restrict__ cw,
            unsigned long long* __restrict__ ws_u64, unsigned* __restrict__ ws_u,
            unsigned* __restrict__ g_seg_u32, unsigned* __restrict__ part,
            unsigned* __restrict__ keys, unsigned* __restrict__ gh1,
            int use_part, int use_keys, int n)
{
    __shared__ unsigned s_seg[4 * NWIN + 4];   // 64 KB + dummy slot
    __shared__ unsigned s_h1[2048];            // 8 KB level-1 histogram
    for (int j = threadIdx.x; j < 4 * NWIN + 4; j += BLOCK_MAIN) s_seg[j] = 0u;
    for (int j = threadIdx.x; j < 2048; j += BLOCK_MAIN) s_h1[j] = 0u;
    __syncthreads();

    const float cw0 = cw[0], cw1 = cw[1];
    float num = 0.0f, den = 0.0f;
    unsigned nv = 0u, nm = 0u, zc = 0u;

    const int nth = GRID_MAIN * BLOCK_MAIN;
    const int gtid = blockIdx.x * BLOCK_MAIN + threadIdx.x;
    const int nq = n >> 2;

    const float4* lg4 = (const float4*)logits;
    const int4* y4p = (const int4*)y;
    const int4* m4p = (const int4*)mask;
    const int4* w4p = (const int4*)widx;

    for (int q = gtid; q < nq; q += nth) {
        float4 lgA = lg4[2 * q], lgB = lg4[2 * q + 1];
        int4 y4 = y4p[q], m4 = m4p[q], w4 = w4p[q];
        // only the .zw halves of x_raw are needed: 8B/elem requested, not 16B
        float2 z0 = xzw[8 * q + 1], z1 = xzw[8 * q + 3];
        float2 z2 = xzw[8 * q + 5], z3 = xzw[8 * q + 7];

        uint4 kq;
        process_elem(lgA.x, lgA.y, y4.x, m4.x, z0.x, z0.y, w4.x,
                     cw0, cw1, &kq.x, num, den, nv, nm, zc, s_seg, s_h1);
        process_elem(lgA.z, lgA.w, y4.y, m4.y, z1.x, z1.y, w4.y,
                     cw0, cw1, &kq.y, num, den, nv, nm, zc, s_seg, s_h1);
        process_elem(lgB.x, lgB.y, y4.z, m4.z, z2.x, z2.y, w4.z,
                     cw0, cw1, &kq.z, num, den, nv, nm, zc, s_seg, s_h1);
        process_elem(lgB.z, lgB.w, y4.w, m4.w, z3.x, z3.y, w4.w,
                     cw0, cw1, &kq.w, num, den, nv, nm, zc, s_seg, s_h1);
        if (use_keys) ((uint4*)keys)[q] = kq;
    }
    for (int i = (nq << 2) + gtid; i < n; i += nth) {   // tail (n%4)
        float2 lg = logits[i];
        float2 zz = xzw[2 * i + 1];
        unsigned k;
        process_elem(lg.x, lg.y, y[i], mask[i], zz.x, zz.y, widx[i],
                     cw0, cw1, &k, num, den, nv, nm, zc, s_seg, s_h1);
        if (use_keys) keys[i] = k;
    }

    for (int off = 32; off > 0; off >>= 1) {
        num += __shfl_down(num, off);
        den += __shfl_down(den, off);
        nv  += __shfl_down(nv, off);
        nm  += __shfl_down(nm, off);
        zc  += __shfl_down(zc, off);
    }
    if ((threadIdx.x & 63) == 0) {
        atomicAdd(&ws_u64[0], (unsigned long long)(num * SCALE_CE + 0.5f));
        atomicAdd(&ws_u64[1], (unsigned long long)(den * SCALE_CE + 0.5f));
        atomicAdd(&ws_u[4], nv);
        atomicAdd(&ws_u[5], nm);
        if (zc) atomicAdd(&s_h1[0], zc);
    }
    __syncthreads();

    if (use_part) {
        uint4* dst = (uint4*)(part + (size_t)blockIdx.x * (4 * NWIN));
        const uint4* src = (const uint4*)s_seg;
        for (int j = threadIdx.x; j < NWIN; j += BLOCK_MAIN) dst[j] = src[j];
    } else {
        for (int j = threadIdx.x; j < 4 * NWIN; j += BLOCK_MAIN) {
            unsigned v = s_seg[j];
            if (v) atomicAdd(&g_seg_u32[j], v);
        }
    }
    for (int j = threadIdx.x; j < 2048; j += BLOCK_MAIN) {
        unsigned v = s_h1[j];
        if (v) atomicAdd(&gh1[j], v);
    }
}

// ---------------- partial reduction: 512 u32 partials -> g_seg_u32 ----------------
extern "C" __global__ __launch_bounds__(256)
void k_reduce(const unsigned* __restrict__ part, unsigned* __restrict__ g_seg_u32)
{
    const int bin = (blockIdx.x & 63) * 256 + threadIdx.x;
    const int c = blockIdx.x >> 6;
    const unsigned* p = part + (size_t)c * (GRID_MAIN / 4) * (4 * NWIN) + bin;
    unsigned s = 0u;
#pragma unroll 8
    for (int b = 0; b < GRID_MAIN / 4; ++b) s += p[(size_t)b * (4 * NWIN)];
    if (s) atomicAdd(&g_seg_u32[bin], s);
}

extern "C" __global__ __launch_bounds__(256)
void k_convert(const unsigned* __restrict__ gsu, float* __restrict__ g_seg)
{
    const int j = blockIdx.x * 256 + threadIdx.x;   // grid 64
    const int c = j & 3;
    double inv = (c == 0) ? 1.0 : (c == 1) ? INV_P : INV_R;
    g_seg[j] = (float)((double)gsu[j] * inv);
}

// ---------------- histogram passes 2 and 3 ----------------
__device__ __forceinline__ void h2_one(unsigned key, unsigned p0, unsigned p1,
                                       unsigned* h)
{
    unsigned top = key >> 21;
    unsigned sub = (key >> 10) & 2047u;
    if (top == p0) atomicAdd(&h[sub], 1u);
    if (top == p1) atomicAdd(&h[2048 + sub], 1u);
}

extern "C" __global__ __launch_bounds__(256)
void k_hist2(const unsigned* __restrict__ keys, const float2* __restrict__ xzw,
             const int* __restrict__ mask, const int* __restrict__ widx,
             int use_keys, int n, const unsigned* __restrict__ ws_u,
             unsigned* __restrict__ gh)
{
    __shared__ unsigned h[2 * 2048];
    for (int j = threadIdx.x; j < 2 * 2048; j += 256) h[j] = 0u;
    __syncthreads();
    const unsigned p0 = ws_u[8], p1 = ws_u[9];
    const int nthr = gridDim.x * blockDim.x;
    const int gtid = blockIdx.x * blockDim.x + threadIdx.x;
    const int nq = n >> 2;
    if (use_keys) {
        const uint4* k4 = (const uint4*)keys;
        int base = gtid;
        for (; base + 3 * nthr < nq; base += 4 * nthr) {
            uint4 a = k4[base], b = k4[base + nthr];
            uint4 c = k4[base + 2 * nthr], d = k4[base + 3 * nthr];
            h2_one(a.x, p0, p1, h); h2_one(a.y, p0, p1, h);
            h2_one(a.z, p0, p1, h); h2_one(a.w, p0, p1, h);
            h2_one(b.x, p0, p1, h); h2_one(b.y, p0, p1, h);
            h2_one(b.z, p0, p1, h); h2_one(b.w, p0, p1, h);
            h2_one(c.x, p0, p1, h); h2_one(c.y, p0, p1, h);
            h2_one(c.z, p0, p1, h); h2_one(c.w, p0, p1, h);
            h2_one(d.x, p0, p1, h); h2_one(d.y, p0, p1, h);
            h2_one(d.z, p0, p1, h); h2_one(d.w, p0, p1, h);
        }
        for (; base < nq; base += nthr) {
            uint4 a = k4[base];
            h2_one(a.x, p0, p1, h); h2_one(a.y, p0, p1, h);
            h2_one(a.z, p0, p1, h); h2_one(a.w, p0, p1, h);
        }
        for (int i = (nq << 2) + gtid; i < n; i += nthr)
            h2_one(keys[i], p0, p1, h);
    } else {
        for (int i = gtid; i < n; i += nthr)
            h2_one(make_key_raw(xzw, mask, widx, i), p0, p1, h);
    }
    __syncthreads();
    for (int j = threadIdx.x; j < 2 * 2048; j += 256)
        if (h[j]) atomicAdd(&gh[j], h[j]);
}

__device__ __forceinline__ void h3_one(unsigned key, unsigned p0, unsigned p1,
                                       unsigned* h)
{
    unsigned top = key >> 10;
    unsigned sub = key & 1023u;
    if (top == p0) atomicAdd(&h[sub], 1u);
    if (top == p1) atomicAdd(&h[1024 + sub], 1u);
}

extern "C" __global__ __launch_bounds__(256)
void k_hist3(const unsigned* __restrict__ keys, const float2* __restrict__ xzw,
             const int* __restrict__ mask, const int* __restrict__ widx,
             int use_keys, int n, const unsigned* __restrict__ ws_u,
             unsigned* __restrict__ gh)
{
    __shared__ unsigned h[2 * 1024];
    for (int j = threadIdx.x; j < 2 * 1024; j += 256) h[j] = 0u;
    __syncthreads();
    const unsigned p0 = ws_u[8], p1 = ws_u[9];
    const int nthr = gridDim.x * blockDim.x;
    const int gtid = blockIdx.x * blockDim.x + threadIdx.x;
    const int nq = n >> 2;
    if (use_keys) {
        const uint4* k4 = (const uint4*)keys;
        int base = gtid;
        for (; base + 3 * nthr < nq; base += 4 * nthr) {
            uint4 a = k4[base], b = k4[base + nthr];
            uint4 c = k4[base + 2 * nthr], d = k4[base + 3 * nthr];
            h3_one(a.x, p0, p1, h); h3_one(a.y, p0, p1, h);
            h3_one(a.z, p0, p1, h); h3_one(a.w, p0, p1, h);
            h3_one(b.x, p0, p1, h); h3_one(b.y, p0, p1, h);
            h3_one(b.z, p0, p1, h); h3_one(b.w, p0, p1, h);
            h3_one(c.x, p0, p1, h); h3_one(c.y, p0, p1, h);
            h3_one(c.z, p0, p1, h); h3_one(c.w, p0, p1, h);
            h3_one(d.x, p0, p1, h); h3_one(d.y, p0, p1, h);
            h3_one(d.z, p0, p1, h); h3_one(d.w, p0, p1, h);
        }
        for (; base < nq; base += nthr) {
            uint4 a = k4[base];
            h3_one(a.x, p0, p1, h); h3_one(a.y, p0, p1, h);
            h3_one(a.z, p0, p1, h); h3_one(a.w, p0, p1, h);
        }
        for (int i = (nq << 2) + gtid; i < n; i += nthr)
            h3_one(keys[i], p0, p1, h);
    } else {
        for (int i = gtid; i < n; i += nthr)
            h3_one(make_key_raw(xzw, mask, widx, i), p0, p1, h);
    }
    __syncthreads();
    for (int j = threadIdx.x; j < 2 * 1024; j += 256)
        if (h[j]) atomicAdd(&gh[j], h[j]);
}

// ---------------- single-block scan + rank search ----------------
__device__ void scan_search(const unsigned* __restrict__ gh, int NB, unsigned rank,
                            unsigned* sv, unsigned* wsb, unsigned* ret)
{
    const int tid = threadIdx.x;
    for (int j = tid; j < NB; j += 256) sv[j] = gh[j];
    __syncthreads();
    const int E = NB >> 8;
    const int base = tid * E;
    unsigned loc = 0u;
    for (int e = 0; e < E; ++e) loc += sv[base + e];
    unsigned inc = loc;
    const int lane = tid & 63;
    for (int off = 1; off < 64; off <<= 1) {
        unsigned u = __shfl_up(inc, off);
        if (lane >= off) inc += u;
    }
    const int wid = tid >> 6;
    if (lane == 63) wsb[wid] = inc;
    __syncthreads();
    if (tid == 0) {
        unsigned run = 0u;
        for (int w = 0; w < 4; ++w) { unsigned t = wsb[w]; wsb[w] = run; run += t; }
    }
    __syncthreads();
    unsigned c = wsb[wid] + (inc - loc);
    for (int e = 0; e < E; ++e) {
        unsigned hv = sv[base + e];
        if (rank >= c && rank < c + hv) { ret[0] = (unsigned)(base + e); ret[1] = rank - c; }
        c += hv;
    }
    __syncthreads();
}

extern "C" __global__ __launch_bounds__(256)
void k_scan1(unsigned* __restrict__ ws_u, float* __restrict__ ws_f,
             const unsigned* __restrict__ gh)
{
    __shared__ unsigned sv[2048];
    __shared__ unsigned wsb[4];
    __shared__ unsigned ret[2];
    __shared__ unsigned rk[2];
    if (threadIdx.x == 0) {
        int n = (int)ws_u[4];
        float nf = (float)(n - 1);
        float pos = fmaxf(0.75f * nf, 0.0f);
        float lo = floorf(pos);
        ws_f[7] = pos - lo;
        rk[0] = (unsigned)lo;
        rk[1] = (unsigned)ceilf(pos);
    }
    __syncthreads();
    unsigned r0 = rk[0], r1 = rk[1];
    scan_search(gh, 2048, r0, sv, wsb, ret);
    if (threadIdx.x == 0) { ws_u[8] = ret[0]; ws_u[10] = ret[1]; }
    scan_search(gh, 2048, r1, sv, wsb, ret);
    if (threadIdx.x == 0) { ws_u[9] = ret[0]; ws_u[11] = ret[1]; }
}

extern "C" __global__ __launch_bounds__(256)
void k_scan2(unsigned* __restrict__ ws_u, const unsigned* __restrict__ gh)
{
    __shared__ unsigned sv[2048];
    __shared__ unsigned wsb[4];
    __shared__ unsigned ret[2];
    unsigned p0 = ws_u[8], p1 = ws_u[9];
    unsigned r0 = ws_u[10], r1 = ws_u[11];
    scan_search(gh, 2048, r0, sv, wsb, ret);
    if (threadIdx.x == 0) { ws_u[8] = (p0 << 11) | ret[0]; ws_u[10] = ret[1]; }
    scan_search(gh + 2048, 2048, r1, sv, wsb, ret);
    if (threadIdx.x == 0) { ws_u[9] = (p1 << 11) | ret[0]; ws_u[11] = ret[1]; }
}

extern "C" __global__ __launch_bounds__(256)
void k_scan3(unsigned* __restrict__ ws_u, float* __restrict__ ws_f,
             const unsigned* __restrict__ gh)
{
    __shared__ unsigned sv[2048];
    __shared__ unsigned wsb[4];
    __shared__ unsigned ret[2];
    unsigned p0 = ws_u[8], p1 = ws_u[9];
    unsigned r0 = ws_u[10], r1 = ws_u[11];
    scan_search(gh, 1024, r0, sv, wsb, ret);
    float v0 = __uint_as_float((p0 << 10) | ret[0]);
    scan_search(gh + 1024, 1024, r1, sv, wsb, ret);
    float v1 = __uint_as_float((p1 << 10) | ret[0]);
    if (threadIdx.x == 0) {
        int n = (int)ws_u[4];
        float frac = ws_f[7];
        float q = v0 * (1.0f - frac) + v1 * frac;
        ws_f[6] = (n > 0) ? fmaxf(q, EPSF) : 1.0f;
    }
}

// ---------------- finalize ----------------
extern "C" __global__ __launch_bounds__(1024)
void k_final(const float* __restrict__ g_seg, const unsigned long long* __restrict__ ws_u64,
             const float* __restrict__ ws_f, const unsigned* __restrict__ ws_u,
             float* __restrict__ out)
{
    __shared__ double red[48];
    const double ref = (double)ws_f[6];
    const float4* gs4 = (const float4*)g_seg;
    double ninc = 0.0, fsum = 0.0, lsum = 0.0;
    for (int w = threadIdx.x; w < NWIN; w += blockDim.x) {
        float4 v = gs4[w];
        double c   = (double)v.x;
        double sp  = (double)v.y;
        double ar  = (double)v.z;
        double spd = (double)v.w;
        double inc = (c >= 2.0 && sp >= 1e-6) ? 1.0 : 0.0;
        double dmean = spd / (sp + 1e-6);
        double rr = ar / (1000.0 + 1e-6);
        double bu = fmax(rr - 1.0, 0.0);
        double flow = bu * bu;
        double rho = fmin(fmax(rr, 0.0), 0.99);
        double dth = 1.0 / (1.0 - rho + 1e-6);
        double lat = fmax(dth - dmean / ref, 0.0);
        ninc += inc; fsum += flow * inc; lsum += lat * inc;
    }
    for (int off = 32; off > 0; off >>= 1) {
        ninc += __shfl_down(ninc, off);
        fsum += __shfl_down(fsum, off);
        lsum += __shfl_down(lsum, off);
    }
    int wid = threadIdx.x >> 6, lane = threadIdx.x & 63;
    if (lane == 0) { red[wid] = ninc; red[16 + wid] = fsum; red[32 + wid] = lsum; }
    __syncthreads();
    if (threadIdx.x == 0) {
        double n_i = 0.0, f_s = 0.0, l_s = 0.0;
        int nw = (int)blockDim.x >> 6;
        for (int w = 0; w < nw; ++w) { n_i += red[w]; f_s += red[16 + w]; l_s += red[32 + w]; }
        double safe = fmax(n_i, 1.0);
        double l_flow = (n_i > 0.0) ? f_s / safe : 0.0;
        double l_lat  = (n_i > 0.0) ? l_s / safe : 0.0;
        double den = (double)ws_u64[1];
        double l_data = (den > 0.0) ? (double)ws_u64[0] / den : 0.0;
        bool any = ws_u[5] > 0u;
        if (!any) { l_data = 0.0; l_flow = 0.0; l_lat = 0.0; }
        out[0] = (float)(l_data + 0.1 * l_flow + 0.1 * l_lat);
        out[1] = (float)l_data;
        out[2] = (float)l_flow;
        out[3] = (float)l_lat;
    }
}

extern "C" void kernel_launch(void* const* d_in, const int* in_sizes, int n_in,
                              void* d_out, int out_size, void* d_ws, size_t ws_size,
                              hipStream_t stream)
{
    const float2* logits = (const float2*)d_in[0];
    const int* y = (const int*)d_in[1];
    const int* mask = (const int*)d_in[2];       // bool delivered as int32
    const float2* xzw = (const float2*)d_in[3];  // x_raw viewed as float2 pairs
    const int* widx = (const int*)d_in[4];
    const float* cw = (const float*)d_in[5];
    float* out = (float*)d_out;
    const int n = in_sizes[1];   // N from y

    unsigned char* ws8 = (unsigned char*)d_ws;
    unsigned long long* ws_u64 = (unsigned long long*)ws8;
    float* ws_f = (float*)ws8;
    unsigned* ws_u = (unsigned*)ws8;
    float* g_seg = (float*)(ws8 + OFF_SEG);
    unsigned* g_h1 = (unsigned*)(ws8 + OFF_H1);
    unsigned* g_h2 = (unsigned*)(ws8 + OFF_H2);
    unsigned* g_h3 = (unsigned*)(ws8 + OFF_H3);
    unsigned* g_seg_u32 = (unsigned*)(ws8 + OFF_SEGU);

    const size_t part_bytes = (size_t)GRID_MAIN * 4 * NWIN * 4;  // 32 MB
    const size_t keys_bytes = (size_t)n * 4u;                    // 16.8 MB
    size_t off = OFF_PART;
    int use_part = 0, use_keys = 0;
    unsigned* part = (unsigned*)(ws8 + off);
    if (ws_size >= off + part_bytes) { use_part = 1; off += part_bytes; }
    unsigned* keys = (unsigned*)(ws8 + off);
    if (ws_size >= off + keys_bytes) { use_keys = 1; off += keys_bytes; }

    // ---- staging tiers: copy inputs to ws via SDMA (different read path) ----
    const size_t xb = (size_t)n * 16u;   // x_raw   67.1 MB
    const size_t lb = (size_t)n * 8u;    // logits  33.6 MB
    const size_t ib = (size_t)n * 4u;    // each int array 16.8 MB
    const float2* xzw_k = xzw;
    const float2* logits_k = logits;
    const int* y_k = y;
    const int* mask_k = mask;
    const int* widx_k = widx;
    void* x_s = nullptr; void* lg_s = nullptr;
    void* y_s = nullptr; void* m_s = nullptr; void* w_s = nullptr;
    if (ws_size >= off + xb) { x_s = ws8 + off; off += xb; }
    if (ws_size >= off + lb) { lg_s = ws8 + off; off += lb; }
    if (ws_size >= off + 3 * ib) {
        y_s = ws8 + off; m_s = ws8 + off + ib; w_s = ws8 + off + 2 * ib;
        off += 3 * ib;
    }

    hipMemsetAsync(d_ws, 0, OFF_PART, stream);   // header + g_seg(+u32) + hists

    if (x_s) {
        hipMemcpyAsync(x_s, (const void*)xzw, xb, hipMemcpyDeviceToDevice, stream);
        xzw_k = (const float2*)x_s;
    }
    if (lg_s) {
        hipMemcpyAsync(lg_s, (const void*)logits, lb, hipMemcpyDeviceToDevice, stream);
        logits_k = (const float2*)lg_s;
    }
    if (y_s) {
        hipMemcpyAsync(y_s, (const void*)y, ib, hipMemcpyDeviceToDevice, stream);
        hipMemcpyAsync(m_s, (const void*)mask, ib, hipMemcpyDeviceToDevice, stream);
        hipMemcpyAsync(w_s, (const void*)widx, ib, hipMemcpyDeviceToDevice, stream);
        y_k = (const int*)y_s; mask_k = (const int*)m_s; widx_k = (const int*)w_s;
    }

    k_main<<<GRID_MAIN, BLOCK_MAIN, 0, stream>>>(logits_k, y_k, mask_k, xzw_k,
                                                 widx_k, cw, ws_u64, ws_u,
                                                 g_seg_u32, part, keys, g_h1,
                                                 use_part, use_keys, n);
    if (use_part)
        k_reduce<<<256, 256, 0, stream>>>(part, g_seg_u32);
    k_convert<<<64, 256, 0, stream>>>(g_seg_u32, g_seg);
    k_scan1<<<1, 256, 0, stream>>>(ws_u, ws_f, g_h1);
    k_hist2<<<1024, 256, 0, stream>>>(keys, xzw_k, mask_k, widx_k, use_keys, n,
                                      ws_u, g_h2);
    k_scan2<<<1, 256, 0, stream>>>(ws_u, g_h2);
    k_hist3<<<1024, 256, 0, stream>>>(keys, xzw_k, mask_k, widx_k, use_keys, n,
                                      ws_u, g_h3);
    k_scan3<<<1, 256, 0, stream>>>(ws_u, ws_f, g_h3);
    k_final<<<1, 1024, 0, stream>>>(g_seg, ws_u64, ws_f, ws_u, out);
}

// Round 11
// 98.801 us; speedup vs baseline: 3.4202x; 3.4202x over previous
//
#include <hip/hip_runtime.h>

#define NWIN 4096
#define EPSF 1e-6f
#define GRID_MAIN 512
#define BLOCK_MAIN 512
#define NWAVES (BLOCK_MAIN / 64)

// fixed-point scales (u32 LDS atomics; native ds_add_u32)
#define SCALE_P   2097152.0f     // 2^21  sum_p
#define SCALE_R   131072.0f      // 2^17  agg_rate / sum_pd
#define INV_P     (1.0/2097152.0)
#define INV_R     (1.0/131072.0)

// ---------------- workspace layout (bytes) ----------------
//  byte 0:  double ce_num     byte 8:  double ce_den
//  byte 16: u32 n_valid(u[4]) byte 20: u32 n_mask(u[5])
//  byte 24: f32 ref_dobs(f[6]) byte 28: f32 frac(f[7])
//  byte 32,36: u32 prefixes (u[8],u[9])  byte 40,44: u32 ranks (u[10],u[11])
#define OFF_SEG   256            // float g_seg[16384] interleaved [wi*4+c]
#define OFF_H1    65792          // u32[2048]
#define OFF_H2    73984          // u32[2*2048]
#define OFF_H3    90368          // u32[2*1024]
#define OFF_CEP   98560          // float ce_part[512*8]  (16 KB, ends 114944)
#define OFF_SEGU  131072         // u32 g_seg_u32[16384] interleaved
#define OFF_PART  262144         // part(32MB) | keys

__device__ __forceinline__ unsigned make_key_raw(const float2* __restrict__ xzw,
                                                 const int* __restrict__ mask,
                                                 const int* __restrict__ widx, int i)
{
    int wi = widx[i];
    int m = mask[i];
    if (wi < 0 || !m) return 0x7F800000u;
    float d = fmaxf(xzw[2 * i + 1].x, 0.0f);
    unsigned k = __float_as_uint(d);
    return (k == 0x80000000u) ? 0u : k;
}

// ---------------- per-element fused work (branchless) ----------------
__device__ __forceinline__ void process_elem(
    float lgx, float lgy, int yi, int mi, float xz, float xw, int wi,
    float cw0, float cw1, unsigned* keyOut,
    float& num, float& den, unsigned& nv, unsigned& nm, unsigned& zc,
    unsigned* s_seg, unsigned* s_h1)
{
    float d = lgx - lgy;
    float ad = fabsf(d);
    float t = __expf(-ad);
    float inv1t = 1.0f / (1.0f + t);
    float l1p = __logf(1.0f + t);
    float s = yi ? d : -d;
    float nll = fmaxf(s, 0.0f) + l1p;
    float maskf = mi ? 1.0f : 0.0f;
    float wy = (yi ? cw1 : cw0) * maskf;
    nm += (mi != 0);
    num += wy * nll;
    den += wy;

    bool vq = (wi >= 0) && mi;
    float dob = fmaxf(xz, 0.0f);
    unsigned kraw = __float_as_uint(dob);
    kraw = (kraw == 0x80000000u) ? 0u : kraw;
    unsigned key = vq ? kraw : 0x7F800000u;
    *keyOut = key;
    nv += vq;
    zc += (key == 0u);

    atomicAdd(&s_h1[key >> 21], (key != 0u) ? 1u : 0u);

    bool sv = vq && ((unsigned)wi < NWIN);
    float sf = sv ? 1.0f : 0.0f;
    unsigned b = sv ? ((unsigned)wi << 2) : (4u * NWIN);
    float p = ((d > 0.0f) ? t : 1.0f) * inv1t;
    float rate = fmaxf(xw, 0.0f);
    atomicAdd(&s_seg[b],     sv ? 1u : 0u);
    atomicAdd(&s_seg[b | 1], (unsigned)(sf * p * SCALE_P + 0.5f));
    atomicAdd(&s_seg[b | 2], (unsigned)(sf * p * rate * SCALE_R + 0.5f));
    atomicAdd(&s_seg[b | 3], (unsigned)(sf * p * dob * SCALE_R + 0.5f));
}

// ---------------- main fused pass (NO global atomics anywhere) ----------------
extern "C" __global__ __launch_bounds__(BLOCK_MAIN)
void k_main(const float2* __restrict__ logits, const int* __restrict__ y,
            const int* __restrict__ mask, const float2* __restrict__ xzw,
            const int* __restrict__ widx, const float* __restrict__ cw,
            float* __restrict__ ce_part,
            unsigned* __restrict__ g_seg_u32, unsigned* __restrict__ part,
            unsigned* __restrict__ keys, unsigned* __restrict__ gh1,
            int use_part, int use_keys, int n)
{
    __shared__ unsigned s_seg[4 * NWIN + 4];   // 64 KB + dummy slot
    __shared__ unsigned s_h1[2048];            // 8 KB level-1 histogram
    __shared__ float s_redf[2 * NWAVES];
    __shared__ unsigned s_redu[3 * NWAVES];
    for (int j = threadIdx.x; j < 4 * NWIN + 4; j += BLOCK_MAIN) s_seg[j] = 0u;
    for (int j = threadIdx.x; j < 2048; j += BLOCK_MAIN) s_h1[j] = 0u;
    __syncthreads();

    const float cw0 = cw[0], cw1 = cw[1];
    float num = 0.0f, den = 0.0f;
    unsigned nv = 0u, nm = 0u, zc = 0u;

    const int nth = GRID_MAIN * BLOCK_MAIN;
    const int gtid = blockIdx.x * BLOCK_MAIN + threadIdx.x;
    const int nq = n >> 2;

    const float4* lg4 = (const float4*)logits;
    const int4* y4p = (const int4*)y;
    const int4* m4p = (const int4*)mask;
    const int4* w4p = (const int4*)widx;

    for (int q = gtid; q < nq; q += nth) {
        float4 lgA = lg4[2 * q], lgB = lg4[2 * q + 1];
        int4 y4 = y4p[q], m4 = m4p[q], w4 = w4p[q];
        float2 z0 = xzw[8 * q + 1], z1 = xzw[8 * q + 3];
        float2 z2 = xzw[8 * q + 5], z3 = xzw[8 * q + 7];

        uint4 kq;
        process_elem(lgA.x, lgA.y, y4.x, m4.x, z0.x, z0.y, w4.x,
                     cw0, cw1, &kq.x, num, den, nv, nm, zc, s_seg, s_h1);
        process_elem(lgA.z, lgA.w, y4.y, m4.y, z1.x, z1.y, w4.y,
                     cw0, cw1, &kq.y, num, den, nv, nm, zc, s_seg, s_h1);
        process_elem(lgB.x, lgB.y, y4.z, m4.z, z2.x, z2.y, w4.z,
                     cw0, cw1, &kq.z, num, den, nv, nm, zc, s_seg, s_h1);
        process_elem(lgB.z, lgB.w, y4.w, m4.w, z3.x, z3.y, w4.w,
                     cw0, cw1, &kq.w, num, den, nv, nm, zc, s_seg, s_h1);
        if (use_keys) ((uint4*)keys)[q] = kq;
    }
    for (int i = (nq << 2) + gtid; i < n; i += nth) {   // tail (n%4)
        float2 lg = logits[i];
        float2 zz = xzw[2 * i + 1];
        unsigned k;
        process_elem(lg.x, lg.y, y[i], mask[i], zz.x, zz.y, widx[i],
                     cw0, cw1, &k, num, den, nv, nm, zc, s_seg, s_h1);
        if (use_keys) keys[i] = k;
    }

    // wave(64) shuffle reduce -> LDS -> one private-slot store per block
    for (int off = 32; off > 0; off >>= 1) {
        num += __shfl_down(num, off);
        den += __shfl_down(den, off);
        nv  += __shfl_down(nv, off);
        nm  += __shfl_down(nm, off);
        zc  += __shfl_down(zc, off);
    }
    const int wid = threadIdx.x >> 6;
    if ((threadIdx.x & 63) == 0) {
        s_redf[wid] = num; s_redf[NWAVES + wid] = den;
        s_redu[wid] = nv; s_redu[NWAVES + wid] = nm; s_redu[2 * NWAVES + wid] = zc;
    }
    __syncthreads();
    if (threadIdx.x == 0) {
        float tn = 0.0f, td = 0.0f;
        unsigned ta = 0u, tb = 0u, tc = 0u;
        for (int w = 0; w < NWAVES; ++w) {
            tn += s_redf[w]; td += s_redf[NWAVES + w];
            ta += s_redu[w]; tb += s_redu[NWAVES + w]; tc += s_redu[2 * NWAVES + w];
        }
        float* cp = ce_part + blockIdx.x * 8;
        cp[0] = tn; cp[1] = td;
        ((unsigned*)cp)[2] = ta; ((unsigned*)cp)[3] = tb; ((unsigned*)cp)[4] = tc;
    }

    if (use_part) {
        uint4* dst = (uint4*)(part + (size_t)blockIdx.x * (4 * NWIN));
        const uint4* src = (const uint4*)s_seg;
        for (int j = threadIdx.x; j < NWIN; j += BLOCK_MAIN) dst[j] = src[j];
    } else {
        for (int j = threadIdx.x; j < 4 * NWIN; j += BLOCK_MAIN) {
            unsigned v = s_seg[j];
            if (v) atomicAdd(&g_seg_u32[j], v);
        }
    }
    for (int j = threadIdx.x; j < 2048; j += BLOCK_MAIN) {
        unsigned v = s_h1[j];
        if (v) atomicAdd(&gh1[j], v);   // ~60 distinct bins/block: fast pattern
    }
}

// ---------------- CE finalize: 512 partials -> header (no atomics) ----------------
extern "C" __global__ __launch_bounds__(512)
void k_cefin(const float* __restrict__ ce_part, double* __restrict__ ws_d,
             unsigned* __restrict__ ws_u, unsigned* __restrict__ gh1)
{
    __shared__ double sd[2 * 8];
    __shared__ unsigned su[3 * 8];
    const int tid = threadIdx.x;
    const float* cp = ce_part + tid * 8;
    double n_ = (double)cp[0];
    double d_ = (double)cp[1];
    unsigned a = ((const unsigned*)cp)[2];
    unsigned b = ((const unsigned*)cp)[3];
    unsigned c = ((const unsigned*)cp)[4];
    for (int off = 32; off > 0; off >>= 1) {
        n_ += __shfl_down(n_, off);
        d_ += __shfl_down(d_, off);
        a  += __shfl_down(a, off);
        b  += __shfl_down(b, off);
        c  += __shfl_down(c, off);
    }
    const int wid = tid >> 6;
    if ((tid & 63) == 0) { sd[wid] = n_; sd[8 + wid] = d_;
                           su[wid] = a; su[8 + wid] = b; su[16 + wid] = c; }
    __syncthreads();
    if (tid == 0) {
        double tn = 0.0, td = 0.0;
        unsigned ta = 0u, tb = 0u, tc = 0u;
        for (int w = 0; w < 8; ++w) {
            tn += sd[w]; td += sd[8 + w];
            ta += su[w]; tb += su[8 + w]; tc += su[16 + w];
        }
        ws_d[0] = tn; ws_d[1] = td;
        ws_u[4] = ta; ws_u[5] = tb;
        gh1[0] += tc;                   // single thread, pre-scan1: no race
    }
}

// ---------------- partial reduction: 512 u32 partials -> g_seg_u32 ----------------
extern "C" __global__ __launch_bounds__(256)
void k_reduce(const unsigned* __restrict__ part, unsigned* __restrict__ g_seg_u32)
{
    const int bin = (blockIdx.x & 63) * 256 + threadIdx.x;
    const int c = blockIdx.x >> 6;
    const unsigned* p = part + (size_t)c * (GRID_MAIN / 4) * (4 * NWIN) + bin;
    unsigned s = 0u;
#pragma unroll 8
    for (int b = 0; b < GRID_MAIN / 4; ++b) s += p[(size_t)b * (4 * NWIN)];
    if (s) atomicAdd(&g_seg_u32[bin], s);
}

extern "C" __global__ __launch_bounds__(256)
void k_convert(const unsigned* __restrict__ gsu, float* __restrict__ g_seg)
{
    const int j = blockIdx.x * 256 + threadIdx.x;   // grid 64
    const int c = j & 3;
    double inv = (c == 0) ? 1.0 : (c == 1) ? INV_P : INV_R;
    g_seg[j] = (float)((double)gsu[j] * inv);
}

// ---------------- histogram passes 2 and 3 ----------------
__device__ __forceinline__ void h2_one(unsigned key, unsigned p0, unsigned p1,
                                       unsigned* h)
{
    unsigned top = key >> 21;
    unsigned sub = (key >> 10) & 2047u;
    if (top == p0) atomicAdd(&h[sub], 1u);
    if (top == p1) atomicAdd(&h[2048 + sub], 1u);
}

extern "C" __global__ __launch_bounds__(256)
void k_hist2(const unsigned* __restrict__ keys, const float2* __restrict__ xzw,
             const int* __restrict__ mask, const int* __restrict__ widx,
             int use_keys, int n, const unsigned* __restrict__ ws_u,
             unsigned* __restrict__ gh)
{
    __shared__ unsigned h[2 * 2048];
    for (int j = threadIdx.x; j < 2 * 2048; j += 256) h[j] = 0u;
    __syncthreads();
    const unsigned p0 = ws_u[8], p1 = ws_u[9];
    const int nthr = gridDim.x * blockDim.x;
    const int gtid = blockIdx.x * blockDim.x + threadIdx.x;
    const int nq = n >> 2;
    if (use_keys) {
        const uint4* k4 = (const uint4*)keys;
        int base = gtid;
        for (; base + 3 * nthr < nq; base += 4 * nthr) {
            uint4 a = k4[base], b = k4[base + nthr];
            uint4 c = k4[base + 2 * nthr], d = k4[base + 3 * nthr];
            h2_one(a.x, p0, p1, h); h2_one(a.y, p0, p1, h);
            h2_one(a.z, p0, p1, h); h2_one(a.w, p0, p1, h);
            h2_one(b.x, p0, p1, h); h2_one(b.y, p0, p1, h);
            h2_one(b.z, p0, p1, h); h2_one(b.w, p0, p1, h);
            h2_one(c.x, p0, p1, h); h2_one(c.y, p0, p1, h);
            h2_one(c.z, p0, p1, h); h2_one(c.w, p0, p1, h);
            h2_one(d.x, p0, p1, h); h2_one(d.y, p0, p1, h);
            h2_one(d.z, p0, p1, h); h2_one(d.w, p0, p1, h);
        }
        for (; base < nq; base += nthr) {
            uint4 a = k4[base];
            h2_one(a.x, p0, p1, h); h2_one(a.y, p0, p1, h);
            h2_one(a.z, p0, p1, h); h2_one(a.w, p0, p1, h);
        }
        for (int i = (nq << 2) + gtid; i < n; i += nthr)
            h2_one(keys[i], p0, p1, h);
    } else {
        for (int i = gtid; i < n; i += nthr)
            h2_one(make_key_raw(xzw, mask, widx, i), p0, p1, h);
    }
    __syncthreads();
    for (int j = threadIdx.x; j < 2 * 2048; j += 256)
        if (h[j]) atomicAdd(&gh[j], h[j]);
}

__device__ __forceinline__ void h3_one(unsigned key, unsigned p0, unsigned p1,
                                       unsigned* h)
{
    unsigned top = key >> 10;
    unsigned sub = key & 1023u;
    if (top == p0) atomicAdd(&h[sub], 1u);
    if (top == p1) atomicAdd(&h[1024 + sub], 1u);
}

extern "C" __global__ __launch_bounds__(256)
void k_hist3(const unsigned* __restrict__ keys, const float2* __restrict__ xzw,
             const int* __restrict__ mask, const int* __restrict__ widx,
             int use_keys, int n, const unsigned* __restrict__ ws_u,
             unsigned* __restrict__ gh)
{
    __shared__ unsigned h[2 * 1024];
    for (int j = threadIdx.x; j < 2 * 1024; j += 256) h[j] = 0u;
    __syncthreads();
    const unsigned p0 = ws_u[8], p1 = ws_u[9];
    const int nthr = gridDim.x * blockDim.x;
    const int gtid = blockIdx.x * blockDim.x + threadIdx.x;
    const int nq = n >> 2;
    if (use_keys) {
        const uint4* k4 = (const uint4*)keys;
        int base = gtid;
        for (; base + 3 * nthr < nq; base += 4 * nthr) {
            uint4 a = k4[base], b = k4[base + nthr];
            uint4 c = k4[base + 2 * nthr], d = k4[base + 3 * nthr];
            h3_one(a.x, p0, p1, h); h3_one(a.y, p0, p1, h);
            h3_one(a.z, p0, p1, h); h3_one(a.w, p0, p1, h);
            h3_one(b.x, p0, p1, h); h3_one(b.y, p0, p1, h);
            h3_one(b.z, p0, p1, h); h3_one(b.w, p0, p1, h);
            h3_one(c.x, p0, p1, h); h3_one(c.y, p0, p1, h);
            h3_one(c.z, p0, p1, h); h3_one(c.w, p0, p1, h);
            h3_one(d.x, p0, p1, h); h3_one(d.y, p0, p1, h);
            h3_one(d.z, p0, p1, h); h3_one(d.w, p0, p1, h);
        }
        for (; base < nq; base += nthr) {
            uint4 a = k4[base];
            h3_one(a.x, p0, p1, h); h3_one(a.y, p0, p1, h);
            h3_one(a.z, p0, p1, h); h3_one(a.w, p0, p1, h);
        }
        for (int i = (nq << 2) + gtid; i < n; i += nthr)
            h3_one(keys[i], p0, p1, h);
    } else {
        for (int i = gtid; i < n; i += nthr)
            h3_one(make_key_raw(xzw, mask, widx, i), p0, p1, h);
    }
    __syncthreads();
    for (int j = threadIdx.x; j < 2 * 1024; j += 256)
        if (h[j]) atomicAdd(&gh[j], h[j]);
}

// ---------------- single-block scan + rank search ----------------
__device__ void scan_search(const unsigned* __restrict__ gh, int NB, unsigned rank,
                            unsigned* sv, unsigned* wsb, unsigned* ret)
{
    const int tid = threadIdx.x;
    for (int j = tid; j < NB; j += 256) sv[j] = gh[j];
    __syncthreads();
    const int E = NB >> 8;
    const int base = tid * E;
    unsigned loc = 0u;
    for (int e = 0; e < E; ++e) loc += sv[base + e];
    unsigned inc = loc;
    const int lane = tid & 63;
    for (int off = 1; off < 64; off <<= 1) {
        unsigned u = __shfl_up(inc, off);
        if (lane >= off) inc += u;
    }
    const int wid = tid >> 6;
    if (lane == 63) wsb[wid] = inc;
    __syncthreads();
    if (tid == 0) {
        unsigned run = 0u;
        for (int w = 0; w < 4; ++w) { unsigned t = wsb[w]; wsb[w] = run; run += t; }
    }
    __syncthreads();
    unsigned c = wsb[wid] + (inc - loc);
    for (int e = 0; e < E; ++e) {
        unsigned hv = sv[base + e];
        if (rank >= c && rank < c + hv) { ret[0] = (unsigned)(base + e); ret[1] = rank - c; }
        c += hv;
    }
    __syncthreads();
}

extern "C" __global__ __launch_bounds__(256)
void k_scan1(unsigned* __restrict__ ws_u, float* __restrict__ ws_f,
             const unsigned* __restrict__ gh)
{
    __shared__ unsigned sv[2048];
    __shared__ unsigned wsb[4];
    __shared__ unsigned ret[2];
    __shared__ unsigned rk[2];
    if (threadIdx.x == 0) {
        int n = (int)ws_u[4];
        float nf = (float)(n - 1);
        float pos = fmaxf(0.75f * nf, 0.0f);
        float lo = floorf(pos);
        ws_f[7] = pos - lo;
        rk[0] = (unsigned)lo;
        rk[1] = (unsigned)ceilf(pos);
    }
    __syncthreads();
    unsigned r0 = rk[0], r1 = rk[1];
    scan_search(gh, 2048, r0, sv, wsb, ret);
    if (threadIdx.x == 0) { ws_u[8] = ret[0]; ws_u[10] = ret[1]; }
    scan_search(gh, 2048, r1, sv, wsb, ret);
    if (threadIdx.x == 0) { ws_u[9] = ret[0]; ws_u[11] = ret[1]; }
}

extern "C" __global__ __launch_bounds__(256)
void k_scan2(unsigned* __restrict__ ws_u, const unsigned* __restrict__ gh)
{
    __shared__ unsigned sv[2048];
    __shared__ unsigned wsb[4];
    __shared__ unsigned ret[2];
    unsigned p0 = ws_u[8], p1 = ws_u[9];
    unsigned r0 = ws_u[10], r1 = ws_u[11];
    scan_search(gh, 2048, r0, sv, wsb, ret);
    if (threadIdx.x == 0) { ws_u[8] = (p0 << 11) | ret[0]; ws_u[10] = ret[1]; }
    scan_search(gh + 2048, 2048, r1, sv, wsb, ret);
    if (threadIdx.x == 0) { ws_u[9] = (p1 << 11) | ret[0]; ws_u[11] = ret[1]; }
}

extern "C" __global__ __launch_bounds__(256)
void k_scan3(unsigned* __restrict__ ws_u, float* __restrict__ ws_f,
             const unsigned* __restrict__ gh)
{
    __shared__ unsigned sv[2048];
    __shared__ unsigned wsb[4];
    __shared__ unsigned ret[2];
    unsigned p0 = ws_u[8], p1 = ws_u[9];
    unsigned r0 = ws_u[10], r1 = ws_u[11];
    scan_search(gh, 1024, r0, sv, wsb, ret);
    float v0 = __uint_as_float((p0 << 10) | ret[0]);
    scan_search(gh + 1024, 1024, r1, sv, wsb, ret);
    float v1 = __uint_as_float((p1 << 10) | ret[0]);
    if (threadIdx.x == 0) {
        int n = (int)ws_u[4];
        float frac = ws_f[7];
        float q = v0 * (1.0f - frac) + v1 * frac;
        ws_f[6] = (n > 0) ? fmaxf(q, EPSF) : 1.0f;
    }
}

// ---------------- finalize ----------------
extern "C" __global__ __launch_bounds__(1024)
void k_final(const float* __restrict__ g_seg, const double* __restrict__ ws_d,
             const float* __restrict__ ws_f, const unsigned* __restrict__ ws_u,
             float* __restrict__ out)
{
    __shared__ double red[48];
    const double ref = (double)ws_f[6];
    const float4* gs4 = (const float4*)g_seg;
    double ninc = 0.0, fsum = 0.0, lsum = 0.0;
    for (int w = threadIdx.x; w < NWIN; w += blockDim.x) {
        float4 v = gs4[w];
        double c   = (double)v.x;
        double sp  = (double)v.y;
        double ar  = (double)v.z;
        double spd = (double)v.w;
        double inc = (c >= 2.0 && sp >= 1e-6) ? 1.0 : 0.0;
        double dmean = spd / (sp + 1e-6);
        double rr = ar / (1000.0 + 1e-6);
        double bu = fmax(rr - 1.0, 0.0);
        double flow = bu * bu;
        double rho = fmin(fmax(rr, 0.0), 0.99);
        double dth = 1.0 / (1.0 - rho + 1e-6);
        double lat = fmax(dth - dmean / ref, 0.0);
        ninc += inc; fsum += flow * inc; lsum += lat * inc;
    }
    for (int off = 32; off > 0; off >>= 1) {
        ninc += __shfl_down(ninc, off);
        fsum += __shfl_down(fsum, off);
        lsum += __shfl_down(lsum, off);
    }
    int wid = threadIdx.x >> 6, lane = threadIdx.x & 63;
    if (lane == 0) { red[wid] = ninc; red[16 + wid] = fsum; red[32 + wid] = lsum; }
    __syncthreads();
    if (threadIdx.x == 0) {
        double n_i = 0.0, f_s = 0.0, l_s = 0.0;
        int nw = (int)blockDim.x >> 6;
        for (int w = 0; w < nw; ++w) { n_i += red[w]; f_s += red[16 + w]; l_s += red[32 + w]; }
        double safe = fmax(n_i, 1.0);
        double l_flow = (n_i > 0.0) ? f_s / safe : 0.0;
        double l_lat  = (n_i > 0.0) ? l_s / safe : 0.0;
        double den = ws_d[1];
        double l_data = ws_d[0] / fmax(den, 1e-12);
        bool any = ws_u[5] > 0u;
        if (!any) { l_data = 0.0; l_flow = 0.0; l_lat = 0.0; }
        out[0] = (float)(l_data + 0.1 * l_flow + 0.1 * l_lat);
        out[1] = (float)l_data;
        out[2] = (float)l_flow;
        out[3] = (float)l_lat;
    }
}

extern "C" void kernel_launch(void* const* d_in, const int* in_sizes, int n_in,
                              void* d_out, int out_size, void* d_ws, size_t ws_size,
                              hipStream_t stream)
{
    const float2* logits = (const float2*)d_in[0];
    const int* y = (const int*)d_in[1];
    const int* mask = (const int*)d_in[2];       // bool delivered as int32
    const float2* xzw = (const float2*)d_in[3];  // x_raw viewed as float2 pairs
    const int* widx = (const int*)d_in[4];
    const float* cw = (const float*)d_in[5];
    float* out = (float*)d_out;
    const int n = in_sizes[1];   // N from y

    unsigned char* ws8 = (unsigned char*)d_ws;
    double* ws_d = (double*)ws8;
    float* ws_f = (float*)ws8;
    unsigned* ws_u = (unsigned*)ws8;
    float* g_seg = (float*)(ws8 + OFF_SEG);
    unsigned* g_h1 = (unsigned*)(ws8 + OFF_H1);
    unsigned* g_h2 = (unsigned*)(ws8 + OFF_H2);
    unsigned* g_h3 = (unsigned*)(ws8 + OFF_H3);
    float* ce_part = (float*)(ws8 + OFF_CEP);
    unsigned* g_seg_u32 = (unsigned*)(ws8 + OFF_SEGU);

    const size_t part_bytes = (size_t)GRID_MAIN * 4 * NWIN * 4;  // 32 MB
    const size_t keys_bytes = (size_t)n * 4u;                    // 16.8 MB
    size_t off = OFF_PART;
    int use_part = 0, use_keys = 0;
    unsigned* part = (unsigned*)(ws8 + off);
    if (ws_size >= off + part_bytes) { use_part = 1; off += part_bytes; }
    unsigned* keys = (unsigned*)(ws8 + off);
    if (ws_size >= off + keys_bytes) { use_keys = 1; }

    hipMemsetAsync(d_ws, 0, OFF_PART, stream);   // header + g_seg(+u32) + hists

    k_main<<<GRID_MAIN, BLOCK_MAIN, 0, stream>>>(logits, y, mask, xzw, widx, cw,
                                                 ce_part, g_seg_u32, part, keys,
                                                 g_h1, use_part, use_keys, n);
    k_cefin<<<1, 512, 0, stream>>>(ce_part, ws_d, ws_u, g_h1);
    if (use_part)
        k_reduce<<<256, 256, 0, stream>>>(part, g_seg_u32);
    k_convert<<<64, 256, 0, stream>>>(g_seg_u32, g_seg);
    k_scan1<<<1, 256, 0, stream>>>(ws_u, ws_f, g_h1);
    k_hist2<<<1024, 256, 0, stream>>>(keys, xzw, mask, widx, use_keys, n, ws_u, g_h2);
    k_scan2<<<1, 256, 0, stream>>>(ws_u, g_h2);
    k_hist3<<<1024, 256, 0, stream>>>(keys, xzw, mask, widx, use_keys, n, ws_u, g_h3);
    k_scan3<<<1, 256, 0, stream>>>(ws_u, ws_f, g_h3);
    k_final<<<1, 1024, 0, stream>>>(g_seg, ws_d, ws_f, ws_u, out);
}

// Round 12
// 91.890 us; speedup vs baseline: 3.6775x; 1.0752x over previous
//
#include <hip/hip_runtime.h>

#define NWIN 4096
#define EPSF 1e-6f
#define GRID_MAIN 512
#define BLOCK_MAIN 512
#define NWAVES (BLOCK_MAIN / 64)

// fixed-point scales (u32 LDS atomics; native ds_add_u32)
#define SCALE_P   2097152.0f     // 2^21  sum_p
#define SCALE_R   131072.0f      // 2^17  agg_rate / sum_pd
#define INV_P     (1.0/2097152.0)
#define INV_R     (1.0/131072.0)

// ---------------- workspace layout (bytes) ----------------
//  byte 0:  double ce_num     byte 8:  double ce_den
//  byte 16: u32 n_valid(u[4]) byte 20: u32 n_mask(u[5])
//  byte 24: f32 ref_dobs(f[6]) byte 28: f32 frac(f[7])
//  byte 32,36: u32 prefixes (u[8],u[9])  byte 40,44: u32 ranks (u[10],u[11])
#define OFF_SEGU  256            // u32 g_seg_u32[16384] interleaved [wi*4+c]
#define OFF_H1    65792          // u32[2048]
#define OFF_H2    73984          // u32[2*2048]
#define OFF_H3    90368          // u32[2*1024]
#define OFF_CEP   98560          // float ce_part[512*8] (16 KB, ends 114944)
#define OFF_PART  131072         // part(32MB) | keys

__device__ __forceinline__ unsigned make_key_raw(const float2* __restrict__ xzw,
                                                 const int* __restrict__ mask,
                                                 const int* __restrict__ widx, int i)
{
    int wi = widx[i];
    int m = mask[i];
    if (wi < 0 || !m) return 0x7F800000u;
    float d = fmaxf(xzw[2 * i + 1].x, 0.0f);
    unsigned k = __float_as_uint(d);
    return (k == 0x80000000u) ? 0u : k;
}

// ---------------- per-element fused work (branchless) ----------------
__device__ __forceinline__ void process_elem(
    float lgx, float lgy, int yi, int mi, float xz, float xw, int wi,
    float cw0, float cw1, unsigned* keyOut,
    float& num, float& den, unsigned& nv, unsigned& nm, unsigned& zc,
    unsigned* s_seg, unsigned* s_h1)
{
    float d = lgx - lgy;
    float ad = fabsf(d);
    float t = __expf(-ad);
    float inv1t = 1.0f / (1.0f + t);
    float l1p = __logf(1.0f + t);
    float s = yi ? d : -d;
    float nll = fmaxf(s, 0.0f) + l1p;
    float maskf = mi ? 1.0f : 0.0f;
    float wy = (yi ? cw1 : cw0) * maskf;
    nm += (mi != 0);
    num += wy * nll;
    den += wy;

    bool vq = (wi >= 0) && mi;
    float dob = fmaxf(xz, 0.0f);
    unsigned kraw = __float_as_uint(dob);
    kraw = (kraw == 0x80000000u) ? 0u : kraw;
    unsigned key = vq ? kraw : 0x7F800000u;
    *keyOut = key;
    nv += vq;
    zc += (key == 0u);

    atomicAdd(&s_h1[key >> 21], (key != 0u) ? 1u : 0u);

    bool sv = vq && ((unsigned)wi < NWIN);
    float sf = sv ? 1.0f : 0.0f;
    unsigned b = sv ? ((unsigned)wi << 2) : (4u * NWIN);
    float p = ((d > 0.0f) ? t : 1.0f) * inv1t;
    float rate = fmaxf(xw, 0.0f);
    atomicAdd(&s_seg[b],     sv ? 1u : 0u);
    atomicAdd(&s_seg[b | 1], (unsigned)(sf * p * SCALE_P + 0.5f));
    atomicAdd(&s_seg[b | 2], (unsigned)(sf * p * rate * SCALE_R + 0.5f));
    atomicAdd(&s_seg[b | 3], (unsigned)(sf * p * dob * SCALE_R + 0.5f));
}

// ---------------- main fused pass (NO global atomics to shared lines) ----------------
extern "C" __global__ __launch_bounds__(BLOCK_MAIN)
void k_main(const float2* __restrict__ logits, const int* __restrict__ y,
            const int* __restrict__ mask, const float2* __restrict__ xzw,
            const int* __restrict__ widx, const float* __restrict__ cw,
            float* __restrict__ ce_part,
            unsigned* __restrict__ g_seg_u32, unsigned* __restrict__ part,
            unsigned* __restrict__ keys, unsigned* __restrict__ gh1,
            int use_part, int use_keys, int n)
{
    __shared__ unsigned s_seg[4 * NWIN + 4];   // 64 KB + dummy slot
    __shared__ unsigned s_h1[2048];            // 8 KB level-1 histogram
    __shared__ float s_redf[2 * NWAVES];
    __shared__ unsigned s_redu[3 * NWAVES];
    for (int j = threadIdx.x; j < 4 * NWIN + 4; j += BLOCK_MAIN) s_seg[j] = 0u;
    for (int j = threadIdx.x; j < 2048; j += BLOCK_MAIN) s_h1[j] = 0u;
    __syncthreads();

    const float cw0 = cw[0], cw1 = cw[1];
    float num = 0.0f, den = 0.0f;
    unsigned nv = 0u, nm = 0u, zc = 0u;

    const int nth = GRID_MAIN * BLOCK_MAIN;
    const int gtid = blockIdx.x * BLOCK_MAIN + threadIdx.x;
    const int nq = n >> 2;

    const float4* lg4 = (const float4*)logits;
    const int4* y4p = (const int4*)y;
    const int4* m4p = (const int4*)mask;
    const int4* w4p = (const int4*)widx;

    for (int q = gtid; q < nq; q += nth) {
        float4 lgA = lg4[2 * q], lgB = lg4[2 * q + 1];
        int4 y4 = y4p[q], m4 = m4p[q], w4 = w4p[q];
        float2 z0 = xzw[8 * q + 1], z1 = xzw[8 * q + 3];
        float2 z2 = xzw[8 * q + 5], z3 = xzw[8 * q + 7];

        uint4 kq;
        process_elem(lgA.x, lgA.y, y4.x, m4.x, z0.x, z0.y, w4.x,
                     cw0, cw1, &kq.x, num, den, nv, nm, zc, s_seg, s_h1);
        process_elem(lgA.z, lgA.w, y4.y, m4.y, z1.x, z1.y, w4.y,
                     cw0, cw1, &kq.y, num, den, nv, nm, zc, s_seg, s_h1);
        process_elem(lgB.x, lgB.y, y4.z, m4.z, z2.x, z2.y, w4.z,
                     cw0, cw1, &kq.z, num, den, nv, nm, zc, s_seg, s_h1);
        process_elem(lgB.z, lgB.w, y4.w, m4.w, z3.x, z3.y, w4.w,
                     cw0, cw1, &kq.w, num, den, nv, nm, zc, s_seg, s_h1);
        if (use_keys) ((uint4*)keys)[q] = kq;
    }
    for (int i = (nq << 2) + gtid; i < n; i += nth) {   // tail (n%4)
        float2 lg = logits[i];
        float2 zz = xzw[2 * i + 1];
        unsigned k;
        process_elem(lg.x, lg.y, y[i], mask[i], zz.x, zz.y, widx[i],
                     cw0, cw1, &k, num, den, nv, nm, zc, s_seg, s_h1);
        if (use_keys) keys[i] = k;
    }

    // wave(64) shuffle reduce -> LDS -> one private-slot store per block
    for (int off = 32; off > 0; off >>= 1) {
        num += __shfl_down(num, off);
        den += __shfl_down(den, off);
        nv  += __shfl_down(nv, off);
        nm  += __shfl_down(nm, off);
        zc  += __shfl_down(zc, off);
    }
    const int wid = threadIdx.x >> 6;
    if ((threadIdx.x & 63) == 0) {
        s_redf[wid] = num; s_redf[NWAVES + wid] = den;
        s_redu[wid] = nv; s_redu[NWAVES + wid] = nm; s_redu[2 * NWAVES + wid] = zc;
    }
    __syncthreads();
    if (threadIdx.x == 0) {
        float tn = 0.0f, td = 0.0f;
        unsigned ta = 0u, tb = 0u, tc = 0u;
        for (int w = 0; w < NWAVES; ++w) {
            tn += s_redf[w]; td += s_redf[NWAVES + w];
            ta += s_redu[w]; tb += s_redu[NWAVES + w]; tc += s_redu[2 * NWAVES + w];
        }
        float* cp = ce_part + blockIdx.x * 8;
        cp[0] = tn; cp[1] = td;
        ((unsigned*)cp)[2] = ta; ((unsigned*)cp)[3] = tb; ((unsigned*)cp)[4] = tc;
    }

    if (use_part) {
        uint4* dst = (uint4*)(part + (size_t)blockIdx.x * (4 * NWIN));
        const uint4* src = (const uint4*)s_seg;
        for (int j = threadIdx.x; j < NWIN; j += BLOCK_MAIN) dst[j] = src[j];
    } else {
        for (int j = threadIdx.x; j < 4 * NWIN; j += BLOCK_MAIN) {
            unsigned v = s_seg[j];
            if (v) atomicAdd(&g_seg_u32[j], v);
        }
    }
    for (int j = threadIdx.x; j < 2048; j += BLOCK_MAIN) {
        unsigned v = s_h1[j];
        if (v) atomicAdd(&gh1[j], v);   // ~60 distinct bins/block: fast pattern
    }
}

// ---------------- generic block-wide scan + rank search (blockDim divides NB or E>=1) ----------------
__device__ void scan_search_g(const unsigned* __restrict__ gh, int NB, unsigned rank,
                              unsigned zadd, unsigned* sv, unsigned* wsb,
                              unsigned* ret)
{
    const int tid = threadIdx.x;
    const int B = blockDim.x;
    for (int j = tid; j < NB; j += B) sv[j] = gh[j] + ((j == 0) ? zadd : 0u);
    __syncthreads();
    const int E = NB / B;            // assumes B divides NB
    const int base = tid * E;
    unsigned loc = 0u;
    for (int e = 0; e < E; ++e) loc += sv[base + e];
    unsigned inc = loc;
    const int lane = tid & 63;
    for (int off = 1; off < 64; off <<= 1) {
        unsigned u = __shfl_up(inc, off);
        if (lane >= off) inc += u;
    }
    const int wid = tid >> 6;
    const int nw = B >> 6;
    if (lane == 63) wsb[wid] = inc;
    __syncthreads();
    if (tid == 0) {
        unsigned run = 0u;
        for (int w = 0; w < nw; ++w) { unsigned t = wsb[w]; wsb[w] = run; run += t; }
    }
    __syncthreads();
    unsigned c = wsb[wid] + (inc - loc);
    for (int e = 0; e < E; ++e) {
        unsigned hv = sv[base + e];
        if (rank >= c && rank < c + hv) { ret[0] = (unsigned)(base + e); ret[1] = rank - c; }
        c += hv;
    }
    __syncthreads();
}

// ---------------- fused post pass: blocks 0-127 reduce partials; block 128 CE+scan1 ----------------
extern "C" __global__ __launch_bounds__(512)
void k_post(const unsigned* __restrict__ part, unsigned* __restrict__ g_seg_u32,
            const float* __restrict__ ce_part, double* __restrict__ ws_d,
            unsigned* __restrict__ ws_u, float* __restrict__ ws_f,
            const unsigned* __restrict__ gh1, int use_part)
{
    if (blockIdx.x < 128) {
        if (!use_part) return;
        // chunk c in 0..3, bin group g in 0..31 -> bin = g*512 + tid
        const int c = blockIdx.x >> 5;
        const int bin = (blockIdx.x & 31) * 512 + threadIdx.x;
        const unsigned* p = part + (size_t)c * 128 * (4 * NWIN) + bin;
        unsigned s = 0u;
#pragma unroll 8
        for (int b = 0; b < 128; ++b) s += p[(size_t)b * (4 * NWIN)];
        if (s) atomicAdd(&g_seg_u32[bin], s);
        return;
    }

    // ---- block 128: CE finalize + level-1 scan ----
    __shared__ unsigned sv[2048];
    __shared__ unsigned wsb[16];
    __shared__ unsigned ret[2];
    __shared__ double sd[2 * 8];
    __shared__ unsigned su[3 * 8];
    __shared__ unsigned bc[4];       // zc_total, n_valid, rank0, rank1
    __shared__ float bf[1];          // frac

    const int tid = threadIdx.x;
    const float* cp = ce_part + tid * 8;
    double n_ = (double)cp[0];
    double d_ = (double)cp[1];
    unsigned a = ((const unsigned*)cp)[2];
    unsigned b = ((const unsigned*)cp)[3];
    unsigned c = ((const unsigned*)cp)[4];
    for (int off = 32; off > 0; off >>= 1) {
        n_ += __shfl_down(n_, off);
        d_ += __shfl_down(d_, off);
        a  += __shfl_down(a, off);
        b  += __shfl_down(b, off);
        c  += __shfl_down(c, off);
    }
    const int wid = tid >> 6;
    if ((tid & 63) == 0) { sd[wid] = n_; sd[8 + wid] = d_;
                           su[wid] = a; su[8 + wid] = b; su[16 + wid] = c; }
    __syncthreads();
    if (tid == 0) {
        double tn = 0.0, td = 0.0;
        unsigned ta = 0u, tb = 0u, tc = 0u;
        for (int w = 0; w < 8; ++w) {
            tn += sd[w]; td += sd[8 + w];
            ta += su[w]; tb += su[8 + w]; tc += su[16 + w];
        }
        ws_d[0] = tn; ws_d[1] = td;
        ws_u[4] = ta; ws_u[5] = tb;
        float nf = (float)((int)ta - 1);
        float pos = fmaxf(0.75f * nf, 0.0f);
        float lo = floorf(pos);
        bf[0] = pos - lo;
        bc[0] = tc;                          // zc total
        bc[1] = ta;                          // n_valid
        bc[2] = (unsigned)lo;                // rank0
        bc[3] = (unsigned)ceilf(pos);        // rank1
    }
    __syncthreads();
    const unsigned zadd = bc[0];
    const unsigned r0 = bc[2], r1 = bc[3];
    if (tid == 0) ws_f[7] = bf[0];

    scan_search_g(gh1, 2048, r0, zadd, sv, wsb, ret);
    if (tid == 0) { ws_u[8] = ret[0]; ws_u[10] = ret[1]; }
    scan_search_g(gh1, 2048, r1, zadd, sv, wsb, ret);
    if (tid == 0) { ws_u[9] = ret[0]; ws_u[11] = ret[1]; }
}

// ---------------- histogram passes 2 and 3 ----------------
__device__ __forceinline__ void h2_one(unsigned key, unsigned p0, unsigned p1,
                                       unsigned* h)
{
    unsigned top = key >> 21;
    unsigned sub = (key >> 10) & 2047u;
    if (top == p0) atomicAdd(&h[sub], 1u);
    if (top == p1) atomicAdd(&h[2048 + sub], 1u);
}

extern "C" __global__ __launch_bounds__(256)
void k_hist2(const unsigned* __restrict__ keys, const float2* __restrict__ xzw,
             const int* __restrict__ mask, const int* __restrict__ widx,
             int use_keys, int n, const unsigned* __restrict__ ws_u,
             unsigned* __restrict__ gh)
{
    __shared__ unsigned h[2 * 2048];
    for (int j = threadIdx.x; j < 2 * 2048; j += 256) h[j] = 0u;
    __syncthreads();
    const unsigned p0 = ws_u[8], p1 = ws_u[9];
    const int nthr = gridDim.x * blockDim.x;
    const int gtid = blockIdx.x * blockDim.x + threadIdx.x;
    const int nq = n >> 2;
    if (use_keys) {
        const uint4* k4 = (const uint4*)keys;
        int base = gtid;
        for (; base + 3 * nthr < nq; base += 4 * nthr) {
            uint4 a = k4[base], b = k4[base + nthr];
            uint4 c = k4[base + 2 * nthr], d = k4[base + 3 * nthr];
            h2_one(a.x, p0, p1, h); h2_one(a.y, p0, p1, h);
            h2_one(a.z, p0, p1, h); h2_one(a.w, p0, p1, h);
            h2_one(b.x, p0, p1, h); h2_one(b.y, p0, p1, h);
            h2_one(b.z, p0, p1, h); h2_one(b.w, p0, p1, h);
            h2_one(c.x, p0, p1, h); h2_one(c.y, p0, p1, h);
            h2_one(c.z, p0, p1, h); h2_one(c.w, p0, p1, h);
            h2_one(d.x, p0, p1, h); h2_one(d.y, p0, p1, h);
            h2_one(d.z, p0, p1, h); h2_one(d.w, p0, p1, h);
        }
        for (; base < nq; base += nthr) {
            uint4 a = k4[base];
            h2_one(a.x, p0, p1, h); h2_one(a.y, p0, p1, h);
            h2_one(a.z, p0, p1, h); h2_one(a.w, p0, p1, h);
        }
        for (int i = (nq << 2) + gtid; i < n; i += nthr)
            h2_one(keys[i], p0, p1, h);
    } else {
        for (int i = gtid; i < n; i += nthr)
            h2_one(make_key_raw(xzw, mask, widx, i), p0, p1, h);
    }
    __syncthreads();
    for (int j = threadIdx.x; j < 2 * 2048; j += 256)
        if (h[j]) atomicAdd(&gh[j], h[j]);
}

extern "C" __global__ __launch_bounds__(256)
void k_scan2(unsigned* __restrict__ ws_u, const unsigned* __restrict__ gh)
{
    __shared__ unsigned sv[2048];
    __shared__ unsigned wsb[16];
    __shared__ unsigned ret[2];
    unsigned p0 = ws_u[8], p1 = ws_u[9];
    unsigned r0 = ws_u[10], r1 = ws_u[11];
    scan_search_g(gh, 2048, r0, 0u, sv, wsb, ret);
    if (threadIdx.x == 0) { ws_u[8] = (p0 << 11) | ret[0]; ws_u[10] = ret[1]; }
    scan_search_g(gh + 2048, 2048, r1, 0u, sv, wsb, ret);
    if (threadIdx.x == 0) { ws_u[9] = (p1 << 11) | ret[0]; ws_u[11] = ret[1]; }
}

__device__ __forceinline__ void h3_one(unsigned key, unsigned p0, unsigned p1,
                                       unsigned* h)
{
    unsigned top = key >> 10;
    unsigned sub = key & 1023u;
    if (top == p0) atomicAdd(&h[sub], 1u);
    if (top == p1) atomicAdd(&h[1024 + sub], 1u);
}

extern "C" __global__ __launch_bounds__(256)
void k_hist3(const unsigned* __restrict__ keys, const float2* __restrict__ xzw,
             const int* __restrict__ mask, const int* __restrict__ widx,
             int use_keys, int n, const unsigned* __restrict__ ws_u,
             unsigned* __restrict__ gh)
{
    __shared__ unsigned h[2 * 1024];
    for (int j = threadIdx.x; j < 2 * 1024; j += 256) h[j] = 0u;
    __syncthreads();
    const unsigned p0 = ws_u[8], p1 = ws_u[9];
    const int nthr = gridDim.x * blockDim.x;
    const int gtid = blockIdx.x * blockDim.x + threadIdx.x;
    const int nq = n >> 2;
    if (use_keys) {
        const uint4* k4 = (const uint4*)keys;
        int base = gtid;
        for (; base + 3 * nthr < nq; base += 4 * nthr) {
            uint4 a = k4[base], b = k4[base + nthr];
            uint4 c = k4[base + 2 * nthr], d = k4[base + 3 * nthr];
            h3_one(a.x, p0, p1, h); h3_one(a.y, p0, p1, h);
            h3_one(a.z, p0, p1, h); h3_one(a.w, p0, p1, h);
            h3_one(b.x, p0, p1, h); h3_one(b.y, p0, p1, h);
            h3_one(b.z, p0, p1, h); h3_one(b.w, p0, p1, h);
            h3_one(c.x, p0, p1, h); h3_one(c.y, p0, p1, h);
            h3_one(c.z, p0, p1, h); h3_one(c.w, p0, p1, h);
            h3_one(d.x, p0, p1, h); h3_one(d.y, p0, p1, h);
            h3_one(d.z, p0, p1, h); h3_one(d.w, p0, p1, h);
        }
        for (; base < nq; base += nthr) {
            uint4 a = k4[base];
            h3_one(a.x, p0, p1, h); h3_one(a.y, p0, p1, h);
            h3_one(a.z, p0, p1, h); h3_one(a.w, p0, p1, h);
        }
        for (int i = (nq << 2) + gtid; i < n; i += nthr)
            h3_one(keys[i], p0, p1, h);
    } else {
        for (int i = gtid; i < n; i += nthr)
            h3_one(make_key_raw(xzw, mask, widx, i), p0, p1, h);
    }
    __syncthreads();
    for (int j = threadIdx.x; j < 2 * 1024; j += 256)
        if (h[j]) atomicAdd(&gh[j], h[j]);
}

// ---------------- finalize: fused scan3 + window loss (1024 threads) ----------------
extern "C" __global__ __launch_bounds__(1024)
void k_final(const unsigned* __restrict__ g_seg_u32, const double* __restrict__ ws_d,
             const float* __restrict__ ws_f, const unsigned* __restrict__ ws_u,
             const unsigned* __restrict__ gh3, float* __restrict__ out)
{
    __shared__ unsigned sv[1024];
    __shared__ unsigned wsb[16];
    __shared__ unsigned ret[2];
    __shared__ double red[48];

    // ---- scan3 (all 1024 threads; E = 1) ----
    const unsigned p0 = ws_u[8], p1 = ws_u[9];
    const unsigned r0 = ws_u[10], r1 = ws_u[11];
    scan_search_g(gh3, 1024, r0, 0u, sv, wsb, ret);
    const float v0 = __uint_as_float((p0 << 10) | ret[0]);
    scan_search_g(gh3 + 1024, 1024, r1, 0u, sv, wsb, ret);
    const float v1 = __uint_as_float((p1 << 10) | ret[0]);

    const int nvalid = (int)ws_u[4];
    const float frac = ws_f[7];
    const float qf = v0 * (1.0f - frac) + v1 * frac;
    const double ref = (double)((nvalid > 0) ? fmaxf(qf, EPSF) : 1.0f);

    // ---- per-window physics terms (g_seg_u32 converted inline) ----
    const uint4* gs4 = (const uint4*)g_seg_u32;
    double ninc = 0.0, fsum = 0.0, lsum = 0.0;
    for (int w = threadIdx.x; w < NWIN; w += blockDim.x) {
        uint4 v = gs4[w];
        double c   = (double)v.x;
        double sp  = (double)v.y * INV_P;
        double ar  = (double)v.z * INV_R;
        double spd = (double)v.w * INV_R;
        double inc = (c >= 2.0 && sp >= 1e-6) ? 1.0 : 0.0;
        double dmean = spd / (sp + 1e-6);
        double rr = ar / (1000.0 + 1e-6);
        double bu = fmax(rr - 1.0, 0.0);
        double flow = bu * bu;
        double rho = fmin(fmax(rr, 0.0), 0.99);
        double dth = 1.0 / (1.0 - rho + 1e-6);
        double lat = fmax(dth - dmean / ref, 0.0);
        ninc += inc; fsum += flow * inc; lsum += lat * inc;
    }
    for (int off = 32; off > 0; off >>= 1) {
        ninc += __shfl_down(ninc, off);
        fsum += __shfl_down(fsum, off);
        lsum += __shfl_down(lsum, off);
    }
    int wid = threadIdx.x >> 6, lane = threadIdx.x & 63;
    if (lane == 0) { red[wid] = ninc; red[16 + wid] = fsum; red[32 + wid] = lsum; }
    __syncthreads();
    if (threadIdx.x == 0) {
        double n_i = 0.0, f_s = 0.0, l_s = 0.0;
        int nw = (int)blockDim.x >> 6;
        for (int w = 0; w < nw; ++w) { n_i += red[w]; f_s += red[16 + w]; l_s += red[32 + w]; }
        double safe = fmax(n_i, 1.0);
        double l_flow = (n_i > 0.0) ? f_s / safe : 0.0;
        double l_lat  = (n_i > 0.0) ? l_s / safe : 0.0;
        double den = ws_d[1];
        double l_data = ws_d[0] / fmax(den, 1e-12);
        bool any = ws_u[5] > 0u;
        if (!any) { l_data = 0.0; l_flow = 0.0; l_lat = 0.0; }
        out[0] = (float)(l_data + 0.1 * l_flow + 0.1 * l_lat);
        out[1] = (float)l_data;
        out[2] = (float)l_flow;
        out[3] = (float)l_lat;
    }
}

extern "C" void kernel_launch(void* const* d_in, const int* in_sizes, int n_in,
                              void* d_out, int out_size, void* d_ws, size_t ws_size,
                              hipStream_t stream)
{
    const float2* logits = (const float2*)d_in[0];
    const int* y = (const int*)d_in[1];
    const int* mask = (const int*)d_in[2];       // bool delivered as int32
    const float2* xzw = (const float2*)d_in[3];  // x_raw viewed as float2 pairs
    const int* widx = (const int*)d_in[4];
    const float* cw = (const float*)d_in[5];
    float* out = (float*)d_out;
    const int n = in_sizes[1];   // N from y

    unsigned char* ws8 = (unsigned char*)d_ws;
    double* ws_d = (double*)ws8;
    float* ws_f = (float*)ws8;
    unsigned* ws_u = (unsigned*)ws8;
    unsigned* g_seg_u32 = (unsigned*)(ws8 + OFF_SEGU);
    unsigned* g_h1 = (unsigned*)(ws8 + OFF_H1);
    unsigned* g_h2 = (unsigned*)(ws8 + OFF_H2);
    unsigned* g_h3 = (unsigned*)(ws8 + OFF_H3);
    float* ce_part = (float*)(ws8 + OFF_CEP);

    const size_t part_bytes = (size_t)GRID_MAIN * 4 * NWIN * 4;  // 32 MB
    const size_t keys_bytes = (size_t)n * 4u;                    // 16.8 MB
    size_t off = OFF_PART;
    int use_part = 0, use_keys = 0;
    unsigned* part = (unsigned*)(ws8 + off);
    if (ws_size >= off + part_bytes) { use_part = 1; off += part_bytes; }
    unsigned* keys = (unsigned*)(ws8 + off);
    if (ws_size >= off + keys_bytes) { use_keys = 1; }

    hipMemsetAsync(d_ws, 0, OFF_PART, stream);   // header + g_seg_u32 + hists

    k_main<<<GRID_MAIN, BLOCK_MAIN, 0, stream>>>(logits, y, mask, xzw, widx, cw,
                                                 ce_part, g_seg_u32, part, keys,
                                                 g_h1, use_part, use_keys, n);
    k_post<<<129, 512, 0, stream>>>(part, g_seg_u32, ce_part, ws_d, ws_u, ws_f,
                                    g_h1, use_part);
    k_hist2<<<1024, 256, 0, stream>>>(keys, xzw, mask, widx, use_keys, n, ws_u, g_h2);
    k_scan2<<<1, 256, 0, stream>>>(ws_u, g_h2);
    k_hist3<<<1024, 256, 0, stream>>>(keys, xzw, mask, widx, use_keys, n, ws_u, g_h3);
    k_final<<<1, 1024, 0, stream>>>(g_seg_u32, ws_d, ws_f, ws_u, g_h3, out);
}